// Round 6
// baseline (536.450 us; speedup 1.0000x reference)
//
#include <hip/hip_runtime.h>
#include <hip/hip_bf16.h>

#define NTOK 8192
#define DM 1024
#define NE 8
#define DH 2048
#define CAP 18432   // 16384 + 8*256 padding, multiple of 256 (tiles must not span experts)

typedef __attribute__((ext_vector_type(8))) short short8;
typedef __attribute__((ext_vector_type(4))) float float4v;

// async global->LDS DMA, 16B per lane; LDS dest is wave-uniform base + lane*16
#define ASYNC_COPY16(gsrc, ldst)                                                              \
    __builtin_amdgcn_global_load_lds((const __attribute__((address_space(1))) unsigned int*)(gsrc), \
                                     (__attribute__((address_space(3))) unsigned int*)(ldst), \
                                     16, 0, 0)

static __device__ __forceinline__ unsigned short f2bf(float f) {
    __hip_bfloat16 h = __float2bfloat16(f);
    return *reinterpret_cast<unsigned short*>(&h);
}

// branch-free gelu, exact-erf form via Abramowitz-Stegun 7.1.26 (|err| < 1.5e-7)
static __device__ __forceinline__ float fast_gelu(float v) {
    float x = v * 0.70710678118654752f;
    float ax = fabsf(x);
    float t = __frcp_rn(1.0f + 0.3275911f * ax);
    float poly = ((((1.061405429f * t - 1.453152027f) * t + 1.421413741f) * t
                   - 0.284496736f) * t + 0.254829592f) * t;
    float y = 1.0f - poly * __expf(-ax * ax);   // erf(|x|)
    float erfv = copysignf(y, x);
    return 0.5f * v * (1.0f + erfv);
}

// ---------------- weight transpose: src [z][R][C] fp32 -> dst [z][C][R] bf16 ----------------

__global__ __launch_bounds__(256) void k_transpose(const float* __restrict__ src,
                                                   __hip_bfloat16* __restrict__ dst,
                                                   int R, int C) {
    __shared__ float t[64][65];
    size_t mat = (size_t)blockIdx.z * R * C;
    src += mat;
    dst += mat;
    int c0 = blockIdx.x * 64, r0 = blockIdx.y * 64;
    int tx = threadIdx.x & 63, ty = threadIdx.x >> 6;  // 64 x 4
#pragma unroll
    for (int i = 0; i < 16; i++) {
        int r = ty + i * 4;
        t[r][tx] = src[(size_t)(r0 + r) * C + c0 + tx];
    }
    __syncthreads();
    int rx = (threadIdx.x & 15) * 4;  // 0..60
    int cy = threadIdx.x >> 4;        // 0..15
#pragma unroll
    for (int i = 0; i < 4; i++) {
        int c = cy + i * 16;
        ushort4 v;
        v.x = f2bf(t[rx + 0][c]);
        v.y = f2bf(t[rx + 1][c]);
        v.z = f2bf(t[rx + 2][c]);
        v.w = f2bf(t[rx + 3][c]);
        *(ushort4*)((unsigned short*)dst + (size_t)(c0 + c) * R + r0 + rx) = v;
    }
}

// ---------------- router (atomic-free; also emits xb = bf16(x)) ----------------

__global__ __launch_bounds__(256) void k_router(const float* __restrict__ x,
                                                const float* __restrict__ rw,
                                                const float* __restrict__ rb,
                                                __hip_bfloat16* __restrict__ xb,
                                                int* __restrict__ topidx,
                                                float* __restrict__ topw,
                                                float* __restrict__ probs8,   // [NTOK][8]
                                                float* __restrict__ zent) {   // [NTOK][2]
    int lane = threadIdx.x & 63, wv = threadIdx.x >> 6;
    int n = blockIdx.x * 4 + wv;
    const float* xr = x + (size_t)n * DM;
    unsigned short* xbr = (unsigned short*)xb + (size_t)n * DM;
    float p[8] = {0.f, 0.f, 0.f, 0.f, 0.f, 0.f, 0.f, 0.f};
#pragma unroll
    for (int i = 0; i < 16; i++) {
        int d = lane + i * 64;
        float xv = xr[d];
        xbr[d] = f2bf(xv);
        const float4* w4 = (const float4*)(rw + (size_t)d * 8);
        float4 wa = w4[0], wb = w4[1];
        p[0] += xv * wa.x; p[1] += xv * wa.y; p[2] += xv * wa.z; p[3] += xv * wa.w;
        p[4] += xv * wb.x; p[5] += xv * wb.y; p[6] += xv * wb.z; p[7] += xv * wb.w;
    }
#pragma unroll
    for (int e = 0; e < 8; e++) {
#pragma unroll
        for (int off = 32; off > 0; off >>= 1) p[e] += __shfl_down(p[e], off);
    }
    if (lane == 0) {
        float logits[8], probs[8];
        float mx = -1e30f;
#pragma unroll
        for (int e = 0; e < 8; e++) {
            logits[e] = p[e] + rb[e];
            mx = fmaxf(mx, logits[e]);
        }
        float se = 0.f;
#pragma unroll
        for (int e = 0; e < 8; e++) {
            probs[e] = __expf(logits[e] - mx);
            se += probs[e];
        }
        float inv = 1.f / se;
        float z = mx + logf(se);
        float ent = 0.f;
#pragma unroll
        for (int e = 0; e < 8; e++) {
            probs[e] *= inv;
            ent -= probs[e] * logf(probs[e] + 1e-10f);
        }
        int i0 = 0;
#pragma unroll
        for (int e = 1; e < 8; e++)
            if (probs[e] > probs[i0]) i0 = e;
        int i1 = (i0 == 0) ? 1 : 0;
#pragma unroll
        for (int e = 0; e < 8; e++)
            if (e != i0 && e != i1 && probs[e] > probs[i1]) i1 = e;
        float w0 = probs[i0], w1v = probs[i1];
        float s = w0 + w1v + 1e-9f;
        topidx[2 * n] = i0;
        topidx[2 * n + 1] = i1;
        topw[2 * n] = w0 / s;
        topw[2 * n + 1] = w1v / s;
        float* pr = probs8 + (size_t)n * 8;
#pragma unroll
        for (int e = 0; e < 8; e++) pr[e] = probs[e];
        zent[2 * n] = z * z;
        zent[2 * n + 1] = ent;
    }
}

// ---------------- route_aux: stats + scan + scatter + finalize, ONE single-block kernel ----------------
// 512 threads = 8 waves; wave e owns expert e. Two ballot/popcount passes (count, place)
// give deterministic race-free slot assignment without atomics; pad rows written here
// (replaces memset); 10 stat sums reduced in-block; 19 output scalars written here
// (replaces k_stats + k_scan + k_scatter + k_finalize + 2 memsets: 12 -> 7 launches).

__global__ __launch_bounds__(512) void k_route_aux(const int* __restrict__ topidx,
                                                   const float* __restrict__ topw,
                                                   const float* __restrict__ probs8,
                                                   const float* __restrict__ zent,
                                                   int* __restrict__ rowtok,
                                                   float* __restrict__ roww,
                                                   int* __restrict__ slot,
                                                   int* __restrict__ offs,
                                                   float* __restrict__ out) {
    int tid = threadIdx.x, lane = tid & 63, wv = tid >> 6;
    __shared__ int cnt_s[8];
    __shared__ int offs_s[9];
    __shared__ float red[8][10];
    unsigned long long ltmask = ((unsigned long long)1 << lane) - 1ull;

    // pass 1: count expert wv's assignments (all lanes track identical wave-uniform cnt)
    int cnt = 0;
    for (int i = lane; i < NTOK; i += 64) {
        int2 v = ((const int2*)topidx)[i];
        unsigned long long m0 = __ballot(v.x == wv);
        unsigned long long m1 = __ballot(v.y == wv);
        cnt += __popcll(m0) + __popcll(m1);
    }
    if (lane == 0) cnt_s[wv] = cnt;
    __syncthreads();
    if (tid == 0) {
        int o = 0;
        for (int e = 0; e < NE; e++) { offs_s[e] = o; o += (cnt_s[e] + 255) & ~255; }
        offs_s[NE] = o;
        for (int e = 0; e <= NE; e++) offs[e] = offs_s[e];
    }
    __syncthreads();
    // pass 2: place rows
    int base = offs_s[wv], pos = 0;
    for (int i = lane; i < NTOK; i += 64) {
        int2 v = ((const int2*)topidx)[i];
        float2 w = ((const float2*)topw)[i];
        unsigned long long m0 = __ballot(v.x == wv);
        if (v.x == wv) {
            int r = base + pos + __popcll(m0 & ltmask);
            rowtok[r] = i; roww[r] = w.x; slot[2 * i] = r;
        }
        pos += __popcll(m0);
        unsigned long long m1 = __ballot(v.y == wv);
        if (v.y == wv) {
            int r = base + pos + __popcll(m1 & ltmask);
            rowtok[r] = i; roww[r] = w.y; slot[2 * i + 1] = r;
        }
        pos += __popcll(m1);
    }
    for (int r = base + cnt + lane; r < offs_s[wv + 1]; r += 64) {
        rowtok[r] = -1; roww[r] = 0.f;   // pad rows
    }
    // stats: sums of probs[8], z^2, entropy
    float s[10];
#pragma unroll
    for (int k = 0; k < 10; k++) s[k] = 0.f;
    for (int i = tid; i < NTOK; i += 512) {
        const float4* p4 = (const float4*)(probs8 + (size_t)i * 8);
        float4 pa = p4[0], pb = p4[1];
        s[0] += pa.x; s[1] += pa.y; s[2] += pa.z; s[3] += pa.w;
        s[4] += pb.x; s[5] += pb.y; s[6] += pb.z; s[7] += pb.w;
        float2 ze = ((const float2*)zent)[i];
        s[8] += ze.x; s[9] += ze.y;
    }
#pragma unroll
    for (int k = 0; k < 10; k++)
#pragma unroll
        for (int off = 32; off > 0; off >>= 1) s[k] += __shfl_down(s[k], off);
    if (lane == 0)
#pragma unroll
        for (int k = 0; k < 10; k++) red[wv][k] = s[k];
    __syncthreads();
    if (tid == 0) {
        const float invN = 1.0f / (float)NTOK;
        float lb = 0.f;
        size_t b = (size_t)NTOK * DM;
        for (int e = 0; e < NE; e++) {
            float sP = 0.f;
            for (int w8 = 0; w8 < 8; w8++) sP += red[w8][e];
            float fe = cnt_s[e] * invN, Pe = sP * invN;
            lb += fe * Pe;
            out[b + 3 + e] = fe;
            out[b + 11 + e] = Pe;
        }
        float z2 = 0.f, en = 0.f;
        for (int w8 = 0; w8 < 8; w8++) { z2 += red[w8][8]; en += red[w8][9]; }
        out[b + 0] = -(float)NE * lb;     // lb_loss
        out[b + 1] = z2 * invN;           // z_loss
        out[b + 2] = en * invN;           // entropy
    }
}

// ---------------- GEMM1: hidden = gelu(x_gathered @ w1 + b1), bf16 out ----------------
// Proven r2-gemm2 structure cloned: 256x128 tile, BK=32, 8 waves (4Mx2N, 64x64/wave),
// triple-buffered 72KB (2 blk/CU), counted vmcnt(3) (tile t+2 stays in flight across the
// barrier; never drains to 0 in steady state), 2 barriers per K-tile.
// 16B-chunk involution swizzle phys = q ^ ((row>>1)&3): staging pre-swizzles the GLOBAL
// src (LDS dest stays linear = tid*16B), reads apply the same XOR -> 2-way banks (free).

#define KT1 (DM / 32)   // 32 K-tiles

__global__ __launch_bounds__(512) void k_gemm1(const __hip_bfloat16* __restrict__ xb,
                                               const __hip_bfloat16* __restrict__ w1T,  // [E][H][D]
                                               const float* __restrict__ b1,            // [E][H]
                                               const int* __restrict__ rowtok,
                                               const int* __restrict__ offs,
                                               __hip_bfloat16* __restrict__ hid) {      // [CAP][DH]
    // 1152 blocks = 8 XCD x (9 row-tiles x 16 col-tiles), col fastest -> A-tile L2 reuse
    int bid = blockIdx.x;
    int ib = bid >> 3;
    int row0 = ((bid & 7) * 9 + (ib >> 4)) * 256;
    if (row0 >= offs[NE]) return;
    int h0 = (ib & 15) * 128;
    int e = 0;
    while (row0 >= offs[e + 1]) e++;
    int tid = threadIdx.x;

    __shared__ __align__(16) short lds[3][12288];  // per buffer: A 16KB (256x32) | B 8KB (128x32)
    __shared__ int tokoff[256];
    if (tid < 256) {
        int t = rowtok[row0 + tid];
        tokoff[tid] = (t < 0 ? 0 : t) * DM;  // pad rows compute on token 0 (output unused)
    }
    __syncthreads();

    int sr = tid >> 2, pc = tid & 3;
    int ch = pc ^ ((sr >> 1) & 3);     // (row+128)>>1&3 == row>>1&3: same swz both halves
    const short* aS0 = (const short*)xb + tokoff[sr] + ch * 8;
    const short* aS1 = (const short*)xb + tokoff[128 + sr] + ch * 8;
    const short* bS  = (const short*)w1T + ((size_t)e * DH + h0 + sr) * DM + ch * 8;
    int ldo = sr * 32 + pc * 8;        // shorts; == tid*16B -> linear dest for global_load_lds

    int lane = tid & 63, wv = tid >> 6;
    int wm = (wv >> 1) * 64, wn = (wv & 1) * 64;   // 4M x 2N waves, 64x64 per wave
    int quad = lane >> 4, l16 = lane & 15;
    int a_off[4], b_off[4];
#pragma unroll
    for (int mt = 0; mt < 4; mt++) {
        int r = wm + mt * 16 + l16;
        a_off[mt] = r * 32 + ((quad ^ ((r >> 1) & 3)) * 8);
    }
#pragma unroll
    for (int nt = 0; nt < 4; nt++) {
        int r = wn + nt * 16 + l16;
        b_off[nt] = 8192 + r * 32 + ((quad ^ ((r >> 1) & 3)) * 8);
    }
    float4v acc[4][4];
#pragma unroll
    for (int i = 0; i < 4; i++)
#pragma unroll
        for (int j = 0; j < 4; j++) {
            float4v z = {0.f, 0.f, 0.f, 0.f};
            acc[i][j] = z;
        }

    // prologue: stage tiles 0,1 into buffers 0,1; wait tile 0 (vmcnt(3): tile 1 may fly)
    ASYNC_COPY16(aS0, &lds[0][ldo]);
    ASYNC_COPY16(aS1, &lds[0][4096 + ldo]);
    ASYNC_COPY16(bS,  &lds[0][8192 + ldo]);
    ASYNC_COPY16(aS0 + 32, &lds[1][ldo]);
    ASYNC_COPY16(aS1 + 32, &lds[1][4096 + ldo]);
    ASYNC_COPY16(bS + 32,  &lds[1][8192 + ldo]);
    asm volatile("s_waitcnt vmcnt(3)" ::: "memory");
    asm volatile("s_barrier" ::: "memory");

    int bi = 0;
#pragma unroll 1
    for (int t = 0; t < KT1; ++t) {
        const short* Ab = &lds[bi][0];
        int sbi = bi + 2; if (sbi >= 3) sbi -= 3;  // (t+2)%3
        int k2 = (t + 2) * 32;
        short8 af[4], bf[4];
#pragma unroll
        for (int mt = 0; mt < 4; mt++) af[mt] = *(const short8*)(Ab + a_off[mt]);
#pragma unroll
        for (int nt = 0; nt < 4; nt++) bf[nt] = *(const short8*)(Ab + b_off[nt]);
        if (t + 2 < KT1) {
            ASYNC_COPY16(aS0 + k2, &lds[sbi][ldo]);
            ASYNC_COPY16(aS1 + k2, &lds[sbi][4096 + ldo]);
            ASYNC_COPY16(bS + k2,  &lds[sbi][8192 + ldo]);
        }
        asm volatile("s_barrier" ::: "memory");
        __builtin_amdgcn_sched_barrier(0);
        __builtin_amdgcn_s_setprio(1);
#pragma unroll
        for (int mt = 0; mt < 4; mt++)
#pragma unroll
            for (int nt = 0; nt < 4; nt++)
                acc[mt][nt] = __builtin_amdgcn_mfma_f32_16x16x32_bf16(af[mt], bf[nt], acc[mt][nt], 0, 0, 0);
        __builtin_amdgcn_s_setprio(0);
        __builtin_amdgcn_sched_barrier(0);
        if (t + 2 < KT1) asm volatile("s_waitcnt vmcnt(3)" ::: "memory");
        else             asm volatile("s_waitcnt vmcnt(0)" ::: "memory");
        asm volatile("s_barrier" ::: "memory");
        bi++; if (bi == 3) bi = 0;
    }

    const float* b1e = b1 + (size_t)e * DH + h0;
#pragma unroll
    for (int mt = 0; mt < 4; mt++) {
#pragma unroll
        for (int nt = 0; nt < 4; nt++) {
            int rl = wm + mt * 16 + quad * 4;
            int cl = wn + nt * 16 + l16;
            float bias = b1e[cl];
#pragma unroll
            for (int r = 0; r < 4; r++) {
                float v = fast_gelu(acc[mt][nt][r] + bias);
                hid[(size_t)(row0 + rl + r) * DH + h0 + cl] = __float2bfloat16(v);
            }
        }
    }
}

// ---------------- GEMM2: outb = (hidden @ w2 + b2) * weight, fp32 out ----------------
// r2 structure verbatim (measured <141us): identical loop, KT=64, plain-store epilogue.

#define KT2 (DH / 32)   // 64 K-tiles

__global__ __launch_bounds__(512) void k_gemm2(const __hip_bfloat16* __restrict__ hid,  // [CAP][DH]
                                               const __hip_bfloat16* __restrict__ w2T,  // [E][D][H]
                                               const float* __restrict__ b2,            // [E][D]
                                               const float* __restrict__ roww,
                                               const int* __restrict__ offs,
                                               float* __restrict__ outb) {              // [CAP][DM]
    int bid = blockIdx.x;
    int ib = bid >> 3;
    int row0 = ((bid & 7) * 9 + (ib >> 3)) * 256;
    if (row0 >= offs[NE]) return;
    int d0 = (ib & 7) * 128;
    int e = 0;
    while (row0 >= offs[e + 1]) e++;
    int tid = threadIdx.x;

    __shared__ __align__(16) short lds[3][12288];  // per buffer: A 16KB | B 8KB

    int sr = tid >> 2, pc = tid & 3;
    int ch = pc ^ ((sr >> 1) & 3);
    const short* aS0 = (const short*)hid + (size_t)(row0 + sr) * DH + ch * 8;
    const short* aS1 = (const short*)hid + (size_t)(row0 + 128 + sr) * DH + ch * 8;
    const short* bS  = (const short*)w2T + ((size_t)e * DM + d0 + sr) * DH + ch * 8;
    int ldo = sr * 32 + pc * 8;

    int lane = tid & 63, wv = tid >> 6;
    int wm = (wv >> 1) * 64, wn = (wv & 1) * 64;   // 4M x 2N waves, 64x64 per wave
    int quad = lane >> 4, l16 = lane & 15;
    int a_off[4], b_off[4];
#pragma unroll
    for (int mt = 0; mt < 4; mt++) {
        int r = wm + mt * 16 + l16;
        a_off[mt] = r * 32 + ((quad ^ ((r >> 1) & 3)) * 8);
    }
#pragma unroll
    for (int nt = 0; nt < 4; nt++) {
        int r = wn + nt * 16 + l16;
        b_off[nt] = 8192 + r * 32 + ((quad ^ ((r >> 1) & 3)) * 8);
    }
    float4v acc[4][4];
#pragma unroll
    for (int i = 0; i < 4; i++)
#pragma unroll
        for (int j = 0; j < 4; j++) {
            float4v z = {0.f, 0.f, 0.f, 0.f};
            acc[i][j] = z;
        }

    ASYNC_COPY16(aS0, &lds[0][ldo]);
    ASYNC_COPY16(aS1, &lds[0][4096 + ldo]);
    ASYNC_COPY16(bS,  &lds[0][8192 + ldo]);
    ASYNC_COPY16(aS0 + 32, &lds[1][ldo]);
    ASYNC_COPY16(aS1 + 32, &lds[1][4096 + ldo]);
    ASYNC_COPY16(bS + 32,  &lds[1][8192 + ldo]);
    asm volatile("s_waitcnt vmcnt(3)" ::: "memory");
    asm volatile("s_barrier" ::: "memory");

    int bi = 0;
#pragma unroll 1
    for (int t = 0; t < KT2; ++t) {
        const short* Ab = &lds[bi][0];
        int sbi = bi + 2; if (sbi >= 3) sbi -= 3;
        int k2 = (t + 2) * 32;
        short8 af[4], bf[4];
#pragma unroll
        for (int mt = 0; mt < 4; mt++) af[mt] = *(const short8*)(Ab + a_off[mt]);
#pragma unroll
        for (int nt = 0; nt < 4; nt++) bf[nt] = *(const short8*)(Ab + b_off[nt]);
        if (t + 2 < KT2) {
            ASYNC_COPY16(aS0 + k2, &lds[sbi][ldo]);
            ASYNC_COPY16(aS1 + k2, &lds[sbi][4096 + ldo]);
            ASYNC_COPY16(bS + k2,  &lds[sbi][8192 + ldo]);
        }
        asm volatile("s_barrier" ::: "memory");
        __builtin_amdgcn_sched_barrier(0);
        __builtin_amdgcn_s_setprio(1);
#pragma unroll
        for (int mt = 0; mt < 4; mt++)
#pragma unroll
            for (int nt = 0; nt < 4; nt++)
                acc[mt][nt] = __builtin_amdgcn_mfma_f32_16x16x32_bf16(af[mt], bf[nt], acc[mt][nt], 0, 0, 0);
        __builtin_amdgcn_s_setprio(0);
        __builtin_amdgcn_sched_barrier(0);
        if (t + 2 < KT2) asm volatile("s_waitcnt vmcnt(3)" ::: "memory");
        else             asm volatile("s_waitcnt vmcnt(0)" ::: "memory");
        asm volatile("s_barrier" ::: "memory");
        bi++; if (bi == 3) bi = 0;
    }

    const float* b2e = b2 + (size_t)e * DM + d0;
#pragma unroll
    for (int mt = 0; mt < 4; mt++) {
#pragma unroll
        for (int nt = 0; nt < 4; nt++) {
            int rl = wm + mt * 16 + quad * 4;
            int cl = wn + nt * 16 + l16;
            float bias = b2e[cl];
#pragma unroll
            for (int r = 0; r < 4; r++) {
                int grow = row0 + rl + r;
                float v = (acc[mt][nt][r] + bias) * roww[grow];
                outb[(size_t)grow * DM + d0 + cl] = v;
            }
        }
    }
}

// ---------------- combine ----------------

__global__ __launch_bounds__(256) void k_combine(const float* __restrict__ outb,
                                                 const int* __restrict__ slot,
                                                 float* __restrict__ y) {
    int n = blockIdx.x;
    int r0 = slot[2 * n], r1 = slot[2 * n + 1];
    const float4* p0 = (const float4*)(outb + (size_t)r0 * DM);
    const float4* p1 = (const float4*)(outb + (size_t)r1 * DM);
    float4 a = p0[threadIdx.x], b = p1[threadIdx.x];
    float4 c;
    c.x = a.x + b.x;
    c.y = a.y + b.y;
    c.z = a.z + b.z;
    c.w = a.w + b.w;
    ((float4*)(y + (size_t)n * DM))[threadIdx.x] = c;
}

// ---------------- launch ----------------

extern "C" void kernel_launch(void* const* d_in, const int* in_sizes, int n_in,
                              void* d_out, int out_size, void* d_ws, size_t ws_size,
                              hipStream_t stream) {
    const float* x  = (const float*)d_in[0];
    const float* rw = (const float*)d_in[1];
    const float* rb = (const float*)d_in[2];
    const float* w1 = (const float*)d_in[3];
    const float* b1 = (const float*)d_in[4];
    const float* w2 = (const float*)d_in[5];
    const float* b2 = (const float*)d_in[6];
    float* out = (float*)d_out;

    char* ws = (char*)d_ws;
    size_t o = 0;
    auto alloc = [&](size_t bytes) {
        size_t r = o;
        o = (o + bytes + 255) & ~(size_t)255;
        return r;
    };
    __hip_bfloat16* w1T = (__hip_bfloat16*)(ws + alloc((size_t)NE * DM * DH * 2));
    __hip_bfloat16* w2T = (__hip_bfloat16*)(ws + alloc((size_t)NE * DM * DH * 2));
    __hip_bfloat16* xb  = (__hip_bfloat16*)(ws + alloc((size_t)NTOK * DM * 2));
    __hip_bfloat16* hid = (__hip_bfloat16*)(ws + alloc((size_t)CAP * DH * 2));
    float* outb = (float*)(ws + alloc((size_t)CAP * DM * 4));
    int* rowtok = (int*)(ws + alloc(CAP * 4));
    float* roww = (float*)(ws + alloc(CAP * 4));
    int* offs   = (int*)(ws + alloc(64));
    int* topidx = (int*)(ws + alloc((size_t)NTOK * 2 * 4));
    float* topw = (float*)(ws + alloc((size_t)NTOK * 2 * 4));
    int* slot   = (int*)(ws + alloc((size_t)NTOK * 2 * 4));
    float* probs8 = (float*)(ws + alloc((size_t)NTOK * 8 * 4));
    float* zent   = (float*)(ws + alloc((size_t)NTOK * 2 * 4));

    k_transpose<<<dim3(DH / 64, DM / 64, NE), 256, 0, stream>>>(w1, w1T, DM, DH);  // -> [E][H][D]
    k_transpose<<<dim3(DM / 64, DH / 64, NE), 256, 0, stream>>>(w2, w2T, DH, DM);  // -> [E][D][H]
    k_router<<<NTOK / 4, 256, 0, stream>>>(x, rw, rb, xb, topidx, topw, probs8, zent);
    k_route_aux<<<1, 512, 0, stream>>>(topidx, topw, probs8, zent, rowtok, roww, slot, offs, out);
    k_gemm1<<<1152, 512, 0, stream>>>(xb, w1T, b1, rowtok, offs, hid);  // 72 row x 16 col tiles
    k_gemm2<<<576, 512, 0, stream>>>(hid, w2T, b2, roww, offs, outb);   // 72 row x 8 col tiles
    k_combine<<<NTOK, 256, 0, stream>>>(outb, slot, out);
}

// Round 10
// 456.265 us; speedup vs baseline: 1.1757x; 1.1757x over previous
//
#include <hip/hip_runtime.h>
#include <hip/hip_bf16.h>

#define NTOK 8192
#define DM 1024
#define NE 8
#define DH 2048
#define CAP 18432   // 16384 + 8*256 padding, multiple of 256 (tiles must not span experts)

typedef __attribute__((ext_vector_type(8))) short short8;
typedef __attribute__((ext_vector_type(4))) float float4v;

// async global->LDS DMA, 16B per lane; LDS dest is wave-uniform base + lane*16
#define ASYNC_COPY16(gsrc, ldst)                                                              \
    __builtin_amdgcn_global_load_lds((const __attribute__((address_space(1))) unsigned int*)(gsrc), \
                                     (__attribute__((address_space(3))) unsigned int*)(ldst), \
                                     16, 0, 0)

static __device__ __forceinline__ unsigned short f2bf(float f) {
    __hip_bfloat16 h = __float2bfloat16(f);
    return *reinterpret_cast<unsigned short*>(&h);
}

// branch-free gelu, exact-erf form via Abramowitz-Stegun 7.1.26 (|err| < 1.5e-7)
static __device__ __forceinline__ float fast_gelu(float v) {
    float x = v * 0.70710678118654752f;
    float ax = fabsf(x);
    float t = __frcp_rn(1.0f + 0.3275911f * ax);
    float poly = ((((1.061405429f * t - 1.453152027f) * t + 1.421413741f) * t
                   - 0.284496736f) * t + 0.254829592f) * t;
    float y = 1.0f - poly * __expf(-ax * ax);   // erf(|x|)
    float erfv = copysignf(y, x);
    return 0.5f * v * (1.0f + erfv);
}

// ---------------- weight transpose: src [z][R][C] fp32 -> dst [z][C][R] bf16 ----------------

__global__ __launch_bounds__(256) void k_transpose(const float* __restrict__ src,
                                                   __hip_bfloat16* __restrict__ dst,
                                                   int R, int C) {
    __shared__ float t[64][65];
    size_t mat = (size_t)blockIdx.z * R * C;
    src += mat;
    dst += mat;
    int c0 = blockIdx.x * 64, r0 = blockIdx.y * 64;
    int tx = threadIdx.x & 63, ty = threadIdx.x >> 6;  // 64 x 4
#pragma unroll
    for (int i = 0; i < 16; i++) {
        int r = ty + i * 4;
        t[r][tx] = src[(size_t)(r0 + r) * C + c0 + tx];
    }
    __syncthreads();
    int rx = (threadIdx.x & 15) * 4;  // 0..60
    int cy = threadIdx.x >> 4;        // 0..15
#pragma unroll
    for (int i = 0; i < 4; i++) {
        int c = cy + i * 16;
        ushort4 v;
        v.x = f2bf(t[rx + 0][c]);
        v.y = f2bf(t[rx + 1][c]);
        v.z = f2bf(t[rx + 2][c]);
        v.w = f2bf(t[rx + 3][c]);
        *(ushort4*)((unsigned short*)dst + (size_t)(c0 + c) * R + r0 + rx) = v;
    }
}

// ---------------- router (atomic-free; also emits xb = bf16(x)) ----------------

__global__ __launch_bounds__(256) void k_router(const float* __restrict__ x,
                                                const float* __restrict__ rw,
                                                const float* __restrict__ rb,
                                                __hip_bfloat16* __restrict__ xb,
                                                int* __restrict__ topidx,
                                                float* __restrict__ topw,
                                                float* __restrict__ probs8,   // [NTOK][8]
                                                float* __restrict__ zent) {   // [NTOK][2]
    int lane = threadIdx.x & 63, wv = threadIdx.x >> 6;
    int n = blockIdx.x * 4 + wv;
    const float* xr = x + (size_t)n * DM;
    unsigned short* xbr = (unsigned short*)xb + (size_t)n * DM;
    float p[8] = {0.f, 0.f, 0.f, 0.f, 0.f, 0.f, 0.f, 0.f};
#pragma unroll
    for (int i = 0; i < 16; i++) {
        int d = lane + i * 64;
        float xv = xr[d];
        xbr[d] = f2bf(xv);
        const float4* w4 = (const float4*)(rw + (size_t)d * 8);
        float4 wa = w4[0], wb = w4[1];
        p[0] += xv * wa.x; p[1] += xv * wa.y; p[2] += xv * wa.z; p[3] += xv * wa.w;
        p[4] += xv * wb.x; p[5] += xv * wb.y; p[6] += xv * wb.z; p[7] += xv * wb.w;
    }
#pragma unroll
    for (int e = 0; e < 8; e++) {
#pragma unroll
        for (int off = 32; off > 0; off >>= 1) p[e] += __shfl_down(p[e], off);
    }
    if (lane == 0) {
        float logits[8], probs[8];
        float mx = -1e30f;
#pragma unroll
        for (int e = 0; e < 8; e++) {
            logits[e] = p[e] + rb[e];
            mx = fmaxf(mx, logits[e]);
        }
        float se = 0.f;
#pragma unroll
        for (int e = 0; e < 8; e++) {
            probs[e] = __expf(logits[e] - mx);
            se += probs[e];
        }
        float inv = 1.f / se;
        float z = mx + logf(se);
        float ent = 0.f;
#pragma unroll
        for (int e = 0; e < 8; e++) {
            probs[e] *= inv;
            ent -= probs[e] * logf(probs[e] + 1e-10f);
        }
        int i0 = 0;
#pragma unroll
        for (int e = 1; e < 8; e++)
            if (probs[e] > probs[i0]) i0 = e;
        int i1 = (i0 == 0) ? 1 : 0;
#pragma unroll
        for (int e = 0; e < 8; e++)
            if (e != i0 && e != i1 && probs[e] > probs[i1]) i1 = e;
        float w0 = probs[i0], w1v = probs[i1];
        float s = w0 + w1v + 1e-9f;
        topidx[2 * n] = i0;
        topidx[2 * n + 1] = i1;
        topw[2 * n] = w0 / s;
        topw[2 * n + 1] = w1v / s;
        float* pr = probs8 + (size_t)n * 8;
#pragma unroll
        for (int e = 0; e < 8; e++) pr[e] = probs[e];
        zent[2 * n] = z * z;
        zent[2 * n + 1] = ent;
    }
}

// ---------------- stats reduction ----------------

__global__ __launch_bounds__(256) void k_stats(const int* __restrict__ topidx,
                                               const float* __restrict__ probs8,
                                               const float* __restrict__ zent,
                                               float* __restrict__ fcnt,
                                               float* __restrict__ sump,
                                               float* __restrict__ szent) {
    int n = blockIdx.x * 256 + threadIdx.x;
    float v[18];
    int e0 = topidx[2 * n], e1 = topidx[2 * n + 1];
#pragma unroll
    for (int e = 0; e < 8; e++) v[e] = (float)((e == e0) + (e == e1));
    const float4* p4 = (const float4*)(probs8 + (size_t)n * 8);
    float4 pa = p4[0], pb = p4[1];
    v[8] = pa.x; v[9] = pa.y; v[10] = pa.z; v[11] = pa.w;
    v[12] = pb.x; v[13] = pb.y; v[14] = pb.z; v[15] = pb.w;
    v[16] = zent[2 * n];
    v[17] = zent[2 * n + 1];
#pragma unroll
    for (int i = 0; i < 18; i++)
#pragma unroll
        for (int off = 32; off > 0; off >>= 1) v[i] += __shfl_down(v[i], off);
    __shared__ float part[4][18];
    int lane = threadIdx.x & 63, wv = threadIdx.x >> 6;
    if (lane == 0)
#pragma unroll
        for (int i = 0; i < 18; i++) part[wv][i] = v[i];
    __syncthreads();
    if (threadIdx.x == 0) {
#pragma unroll
        for (int i = 0; i < 18; i++) {
            float s = part[0][i] + part[1][i] + part[2][i] + part[3][i];
            if (i < 8) atomicAdd(&fcnt[i], s);
            else if (i < 16) atomicAdd(&sump[i - 8], s);
            else atomicAdd(&szent[i - 16], s);
        }
    }
}

// ---------------- scan + scatter ----------------

__global__ void k_scan(const float* __restrict__ fcnt, int* __restrict__ offs) {
    if (threadIdx.x == 0 && blockIdx.x == 0) {
        int o = 0;
        for (int e = 0; e < NE; e++) {
            offs[e] = o;
            int c = (int)(fcnt[e] + 0.5f);
            o += (c + 255) & ~255;   // align 256: GEMM row-tiles never span experts
        }
        offs[NE] = o;
    }
}

__global__ __launch_bounds__(256) void k_scatter(const int* __restrict__ topidx,
                                                 const float* __restrict__ topw,
                                                 const int* __restrict__ offs,
                                                 int* __restrict__ cnt2,
                                                 int* __restrict__ rowtok,
                                                 float* __restrict__ roww,
                                                 int* __restrict__ slot) {
    __shared__ int lcnt[8], lbase[8];
    int tid = threadIdx.x;
    if (tid < 8) lcnt[tid] = 0;
    __syncthreads();
    int n = blockIdx.x * 256 + tid;
    int e0 = topidx[2 * n], e1 = topidx[2 * n + 1];
    int p0 = atomicAdd(&lcnt[e0], 1);
    int p1 = atomicAdd(&lcnt[e1], 1);
    __syncthreads();
    if (tid < 8) lbase[tid] = atomicAdd(&cnt2[tid], lcnt[tid]);
    __syncthreads();
    int r0 = offs[e0] + lbase[e0] + p0;
    int r1 = offs[e1] + lbase[e1] + p1;
    rowtok[r0] = n; roww[r0] = topw[2 * n];     slot[2 * n] = r0;
    rowtok[r1] = n; roww[r1] = topw[2 * n + 1]; slot[2 * n + 1] = r1;
}

// ---------------- GEMM1: hidden = gelu(x_gathered @ w1 + b1), bf16 out ----------------
// 256x128 tile, BK=32, 8 waves (4Mx2N, 64x64/wave), DOUBLE-buffered LDS 48KB ->
// 3 blocks/CU (24 waves/CU; r6 measured 1->2 blk/CU = 1.23x, this takes the next step).
// m97 semantics: stage(t+1 -> buf^1) issued FIRST, ds_read(buf) + MFMA, then one
// vmcnt(0) drain + barrier per K-tile; each block's drain stall is covered by the other
// two resident blocks (m114 overlap). NO launch_bounds min-waves arg (r4's fatal clamp).
// 16B-chunk involution swizzle phys = q ^ ((row>>1)&3): staging pre-swizzles the GLOBAL
// src (LDS dest stays linear = tid*16B), reads apply the same XOR -> 2-way banks (free).

#define KT1 (DM / 32)   // 32 K-tiles

__global__ __launch_bounds__(512) void k_gemm1(const __hip_bfloat16* __restrict__ xb,
                                               const __hip_bfloat16* __restrict__ w1T,  // [E][H][D]
                                               const float* __restrict__ b1,            // [E][H]
                                               const int* __restrict__ rowtok,
                                               const int* __restrict__ offs,
                                               __hip_bfloat16* __restrict__ hid) {      // [CAP][DH]
    // 1152 blocks = 8 XCD x (9 row-tiles x 16 col-tiles), col fastest -> A-tile L2 reuse
    int bid = blockIdx.x;
    int ib = bid >> 3;
    int row0 = ((bid & 7) * 9 + (ib >> 4)) * 256;
    if (row0 >= offs[NE]) return;
    int h0 = (ib & 15) * 128;
    int e = 0;
    while (row0 >= offs[e + 1]) e++;
    int tid = threadIdx.x;

    __shared__ __align__(16) short lds[2][12288];  // 48KB: per buffer A 16KB (256x32) | B 8KB (128x32)
    __shared__ int tokoff[256];
    if (tid < 256) {
        int t = rowtok[row0 + tid];
        tokoff[tid] = (t < 0 ? 0 : t) * DM;  // pad rows compute on token 0 (output unused)
    }
    __syncthreads();

    int sr = tid >> 2, pc = tid & 3;
    int ch = pc ^ ((sr >> 1) & 3);     // (row+128)>>1&3 == row>>1&3: same swz both halves
    const short* aS0 = (const short*)xb + tokoff[sr] + ch * 8;
    const short* aS1 = (const short*)xb + tokoff[128 + sr] + ch * 8;
    const short* bS  = (const short*)w1T + ((size_t)e * DH + h0 + sr) * DM + ch * 8;
    int ldo = sr * 32 + pc * 8;        // shorts; == tid*16B -> linear dest for global_load_lds

    int lane = tid & 63, wv = tid >> 6;
    int wm = (wv >> 1) * 64, wn = (wv & 1) * 64;   // 4M x 2N waves, 64x64 per wave
    int quad = lane >> 4, l16 = lane & 15;
    int a_off[4], b_off[4];
#pragma unroll
    for (int mt = 0; mt < 4; mt++) {
        int r = wm + mt * 16 + l16;
        a_off[mt] = r * 32 + ((quad ^ ((r >> 1) & 3)) * 8);
    }
#pragma unroll
    for (int nt = 0; nt < 4; nt++) {
        int r = wn + nt * 16 + l16;
        b_off[nt] = 8192 + r * 32 + ((quad ^ ((r >> 1) & 3)) * 8);
    }
    float4v acc[4][4];
#pragma unroll
    for (int i = 0; i < 4; i++)
#pragma unroll
        for (int j = 0; j < 4; j++) {
            float4v z = {0.f, 0.f, 0.f, 0.f};
            acc[i][j] = z;
        }

    // prologue: stage tile 0 into buffer 0, drain
    ASYNC_COPY16(aS0, &lds[0][ldo]);
    ASYNC_COPY16(aS1, &lds[0][4096 + ldo]);
    ASYNC_COPY16(bS,  &lds[0][8192 + ldo]);
    asm volatile("s_waitcnt vmcnt(0)" ::: "memory");
    asm volatile("s_barrier" ::: "memory");

    int buf = 0;
#pragma unroll 1
    for (int t = 0; t < KT1; ++t) {
        const short* Ab = &lds[buf][0];
        int k1 = (t + 1) * 32;
        if (t + 1 < KT1) {  // stage next tile into the other buffer (its reads done last iter)
            ASYNC_COPY16(aS0 + k1, &lds[buf ^ 1][ldo]);
            ASYNC_COPY16(aS1 + k1, &lds[buf ^ 1][4096 + ldo]);
            ASYNC_COPY16(bS + k1,  &lds[buf ^ 1][8192 + ldo]);
        }
        short8 af[4], bf[4];
#pragma unroll
        for (int mt = 0; mt < 4; mt++) af[mt] = *(const short8*)(Ab + a_off[mt]);
#pragma unroll
        for (int nt = 0; nt < 4; nt++) bf[nt] = *(const short8*)(Ab + b_off[nt]);
        __builtin_amdgcn_s_setprio(1);
#pragma unroll
        for (int mt = 0; mt < 4; mt++)
#pragma unroll
            for (int nt = 0; nt < 4; nt++)
                acc[mt][nt] = __builtin_amdgcn_mfma_f32_16x16x32_bf16(af[mt], bf[nt], acc[mt][nt], 0, 0, 0);
        __builtin_amdgcn_s_setprio(0);
        // next tile fully landed (all waves) before anyone reads it next iter;
        // this block's drain stall is covered by the other 2 resident blocks (m114)
        asm volatile("s_waitcnt vmcnt(0)" ::: "memory");
        asm volatile("s_barrier" ::: "memory");
        buf ^= 1;
    }

    const float* b1e = b1 + (size_t)e * DH + h0;
#pragma unroll
    for (int mt = 0; mt < 4; mt++) {
#pragma unroll
        for (int nt = 0; nt < 4; nt++) {
            int rl = wm + mt * 16 + quad * 4;
            int cl = wn + nt * 16 + l16;
            float bias = b1e[cl];
#pragma unroll
            for (int r = 0; r < 4; r++) {
                float v = fast_gelu(acc[mt][nt][r] + bias);
                hid[(size_t)(row0 + rl + r) * DH + h0 + cl] = __float2bfloat16(v);
            }
        }
    }
}

// ---------------- GEMM2: outb = (hidden @ w2 + b2) * weight, fp32 out ----------------
// Same 256x128 / 48KB double-buffer / 3-blk-per-CU / one-barrier-per-K-tile structure.

#define KT2 (DH / 32)   // 64 K-tiles

__global__ __launch_bounds__(512) void k_gemm2(const __hip_bfloat16* __restrict__ hid,  // [CAP][DH]
                                               const __hip_bfloat16* __restrict__ w2T,  // [E][D][H]
                                               const float* __restrict__ b2,            // [E][D]
                                               const float* __restrict__ roww,
                                               const int* __restrict__ offs,
                                               float* __restrict__ outb) {              // [CAP][DM]
    int bid = blockIdx.x;
    int ib = bid >> 3;
    int row0 = ((bid & 7) * 9 + (ib >> 3)) * 256;
    if (row0 >= offs[NE]) return;
    int d0 = (ib & 7) * 128;
    int e = 0;
    while (row0 >= offs[e + 1]) e++;
    int tid = threadIdx.x;

    __shared__ __align__(16) short lds[2][12288];  // 48KB: per buffer A 16KB | B 8KB

    int sr = tid >> 2, pc = tid & 3;
    int ch = pc ^ ((sr >> 1) & 3);
    const short* aS0 = (const short*)hid + (size_t)(row0 + sr) * DH + ch * 8;
    const short* aS1 = (const short*)hid + (size_t)(row0 + 128 + sr) * DH + ch * 8;
    const short* bS  = (const short*)w2T + ((size_t)e * DM + d0 + sr) * DH + ch * 8;
    int ldo = sr * 32 + pc * 8;

    int lane = tid & 63, wv = tid >> 6;
    int wm = (wv >> 1) * 64, wn = (wv & 1) * 64;   // 4M x 2N waves, 64x64 per wave
    int quad = lane >> 4, l16 = lane & 15;
    int a_off[4], b_off[4];
#pragma unroll
    for (int mt = 0; mt < 4; mt++) {
        int r = wm + mt * 16 + l16;
        a_off[mt] = r * 32 + ((quad ^ ((r >> 1) & 3)) * 8);
    }
#pragma unroll
    for (int nt = 0; nt < 4; nt++) {
        int r = wn + nt * 16 + l16;
        b_off[nt] = 8192 + r * 32 + ((quad ^ ((r >> 1) & 3)) * 8);
    }
    float4v acc[4][4];
#pragma unroll
    for (int i = 0; i < 4; i++)
#pragma unroll
        for (int j = 0; j < 4; j++) {
            float4v z = {0.f, 0.f, 0.f, 0.f};
            acc[i][j] = z;
        }

    ASYNC_COPY16(aS0, &lds[0][ldo]);
    ASYNC_COPY16(aS1, &lds[0][4096 + ldo]);
    ASYNC_COPY16(bS,  &lds[0][8192 + ldo]);
    asm volatile("s_waitcnt vmcnt(0)" ::: "memory");
    asm volatile("s_barrier" ::: "memory");

    int buf = 0;
#pragma unroll 1
    for (int t = 0; t < KT2; ++t) {
        const short* Ab = &lds[buf][0];
        int k1 = (t + 1) * 32;
        if (t + 1 < KT2) {
            ASYNC_COPY16(aS0 + k1, &lds[buf ^ 1][ldo]);
            ASYNC_COPY16(aS1 + k1, &lds[buf ^ 1][4096 + ldo]);
            ASYNC_COPY16(bS + k1,  &lds[buf ^ 1][8192 + ldo]);
        }
        short8 af[4], bf[4];
#pragma unroll
        for (int mt = 0; mt < 4; mt++) af[mt] = *(const short8*)(Ab + a_off[mt]);
#pragma unroll
        for (int nt = 0; nt < 4; nt++) bf[nt] = *(const short8*)(Ab + b_off[nt]);
        __builtin_amdgcn_s_setprio(1);
#pragma unroll
        for (int mt = 0; mt < 4; mt++)
#pragma unroll
            for (int nt = 0; nt < 4; nt++)
                acc[mt][nt] = __builtin_amdgcn_mfma_f32_16x16x32_bf16(af[mt], bf[nt], acc[mt][nt], 0, 0, 0);
        __builtin_amdgcn_s_setprio(0);
        asm volatile("s_waitcnt vmcnt(0)" ::: "memory");
        asm volatile("s_barrier" ::: "memory");
        buf ^= 1;
    }

    const float* b2e = b2 + (size_t)e * DM + d0;
#pragma unroll
    for (int mt = 0; mt < 4; mt++) {
#pragma unroll
        for (int nt = 0; nt < 4; nt++) {
            int rl = wm + mt * 16 + quad * 4;
            int cl = wn + nt * 16 + l16;
            float bias = b2e[cl];
#pragma unroll
            for (int r = 0; r < 4; r++) {
                int grow = row0 + rl + r;
                float v = (acc[mt][nt][r] + bias) * roww[grow];
                outb[(size_t)grow * DM + d0 + cl] = v;
            }
        }
    }
}

// ---------------- combine + finalize ----------------

__global__ __launch_bounds__(256) void k_combine(const float* __restrict__ outb,
                                                 const int* __restrict__ slot,
                                                 float* __restrict__ y) {
    int n = blockIdx.x;
    int r0 = slot[2 * n], r1 = slot[2 * n + 1];
    const float4* p0 = (const float4*)(outb + (size_t)r0 * DM);
    const float4* p1 = (const float4*)(outb + (size_t)r1 * DM);
    float4 a = p0[threadIdx.x], b = p1[threadIdx.x];
    float4 c;
    c.x = a.x + b.x;
    c.y = a.y + b.y;
    c.z = a.z + b.z;
    c.w = a.w + b.w;
    ((float4*)(y + (size_t)n * DM))[threadIdx.x] = c;
}

__global__ void k_finalize(const float* __restrict__ fcnt, const float* __restrict__ sump,
                           const float* __restrict__ szent, float* __restrict__ out) {
    if (threadIdx.x == 0 && blockIdx.x == 0) {
        const float invN = 1.0f / (float)NTOK;
        float lb = 0.f;
        float f[NE], P[NE];
        for (int e = 0; e < NE; e++) {
            f[e] = fcnt[e] * invN;
            P[e] = sump[e] * invN;
            lb += f[e] * P[e];
        }
        size_t base = (size_t)NTOK * DM;
        out[base + 0] = -(float)NE * lb;      // lb_loss
        out[base + 1] = szent[0] * invN;      // z_loss
        out[base + 2] = szent[1] * invN;      // entropy
        for (int e = 0; e < NE; e++) out[base + 3 + e] = f[e];
        for (int e = 0; e < NE; e++) out[base + 11 + e] = P[e];
    }
}

// ---------------- launch ----------------

extern "C" void kernel_launch(void* const* d_in, const int* in_sizes, int n_in,
                              void* d_out, int out_size, void* d_ws, size_t ws_size,
                              hipStream_t stream) {
    const float* x  = (const float*)d_in[0];
    const float* rw = (const float*)d_in[1];
    const float* rb = (const float*)d_in[2];
    const float* w1 = (const float*)d_in[3];
    const float* b1 = (const float*)d_in[4];
    const float* w2 = (const float*)d_in[5];
    const float* b2 = (const float*)d_in[6];
    float* out = (float*)d_out;

    char* ws = (char*)d_ws;
    size_t o = 0;
    auto alloc = [&](size_t bytes) {
        size_t r = o;
        o = (o + bytes + 255) & ~(size_t)255;
        return r;
    };
    __hip_bfloat16* w1T = (__hip_bfloat16*)(ws + alloc((size_t)NE * DM * DH * 2));
    __hip_bfloat16* w2T = (__hip_bfloat16*)(ws + alloc((size_t)NE * DM * DH * 2));
    __hip_bfloat16* xb  = (__hip_bfloat16*)(ws + alloc((size_t)NTOK * DM * 2));
    __hip_bfloat16* hid = (__hip_bfloat16*)(ws + alloc((size_t)CAP * DH * 2));
    float* outb = (float*)(ws + alloc((size_t)CAP * DM * 4));
    int* rowtok = (int*)(ws + alloc(CAP * 4));
    size_t zstart = o;
    float* roww  = (float*)(ws + alloc(CAP * 4));
    float* fcnt  = (float*)(ws + alloc(64));
    int* cnt2    = (int*)(ws + alloc(64));
    int* offs    = (int*)(ws + alloc(64));
    float* sump  = (float*)(ws + alloc(64));
    float* szent = (float*)(ws + alloc(64));
    size_t zend = o;
    int* topidx = (int*)(ws + alloc((size_t)NTOK * 2 * 4));
    float* topw = (float*)(ws + alloc((size_t)NTOK * 2 * 4));
    int* slot   = (int*)(ws + alloc((size_t)NTOK * 2 * 4));
    float* probs8 = (float*)(ws + alloc((size_t)NTOK * 8 * 4));
    float* zent   = (float*)(ws + alloc((size_t)NTOK * 2 * 4));

    hipMemsetAsync(rowtok, 0xFF, (size_t)CAP * 4, stream);   // pad rows -> token -1
    hipMemsetAsync(ws + zstart, 0, zend - zstart, stream);   // weights/counters/stats

    k_transpose<<<dim3(DH / 64, DM / 64, NE), 256, 0, stream>>>(w1, w1T, DM, DH);  // -> [E][H][D]
    k_transpose<<<dim3(DM / 64, DH / 64, NE), 256, 0, stream>>>(w2, w2T, DH, DM);  // -> [E][D][H]
    k_router<<<NTOK / 4, 256, 0, stream>>>(x, rw, rb, xb, topidx, topw, probs8, zent);
    k_stats<<<NTOK / 256, 256, 0, stream>>>(topidx, probs8, zent, fcnt, sump, szent);
    k_scan<<<1, 1, 0, stream>>>(fcnt, offs);
    k_scatter<<<NTOK / 256, 256, 0, stream>>>(topidx, topw, offs, cnt2, rowtok, roww, slot);
    k_gemm1<<<1152, 512, 0, stream>>>(xb, w1T, b1, rowtok, offs, hid);  // 72 row x 16 col tiles
    k_gemm2<<<576, 512, 0, stream>>>(hid, w2T, b2, roww, offs, outb);   // 72 row x 8 col tiles
    k_combine<<<NTOK, 256, 0, stream>>>(outb, slot, out);
    k_finalize<<<1, 1, 0, stream>>>(fcnt, sump, szent, out);
}